// Round 6
// baseline (5420.331 us; speedup 1.0000x reference)
//
#include <hip/hip_runtime.h>

typedef short s8v __attribute__((ext_vector_type(8)));   // 8 x bf16 bits
typedef float f4v __attribute__((ext_vector_type(4)));
typedef unsigned short u16;

#define CH 128          // timesteps per chunk
#define NCH 4
#define NRB 128         // rec blocks; each owns 8 hidden units (32 gate cols)

__device__ __forceinline__ u16 f2bf(float f) {
  unsigned u = __builtin_bit_cast(unsigned, f);
  u = (u + 0x7fffu + ((u >> 16) & 1u)) >> 16;
  return (u16)u;
}
__device__ __forceinline__ float bf2f(u16 h) {
  unsigned u = ((unsigned)h) << 16;
  return __builtin_bit_cast(float, u);
}

// ------- cast inputs to bf16, combine bias, stage h0 (bf16) and c0 -------
__global__ void k_cast(const float* __restrict__ x, const float* __restrict__ wih,
                       const float* __restrict__ whh, const float* __restrict__ bih,
                       const float* __restrict__ bhh, const float* __restrict__ h0,
                       const float* __restrict__ c0, u16* __restrict__ xb,
                       u16* __restrict__ wihb, u16* __restrict__ whhb,
                       float* __restrict__ bias, u16* __restrict__ hbuf,
                       float* __restrict__ cst) {
  unsigned i = blockIdx.x * 256u + threadIdx.x;
  const unsigned NT = 8192u * 256u;
  for (unsigned j = i; j < 8388608u; j += NT) {          // x: 33.5M els as float4
    float4 v = ((const float4*)x)[j];
    ushort4 o; o.x = f2bf(v.x); o.y = f2bf(v.y); o.z = f2bf(v.z); o.w = f2bf(v.w);
    ((ushort4*)xb)[j] = o;
  }
  if (i < 1048576u) {                                    // w_ih, w_hh
    float4 v = ((const float4*)wih)[i];
    ushort4 o; o.x = f2bf(v.x); o.y = f2bf(v.y); o.z = f2bf(v.z); o.w = f2bf(v.w);
    ((ushort4*)wihb)[i] = o;
    float4 w = ((const float4*)whh)[i];
    ushort4 p; p.x = f2bf(w.x); p.y = f2bf(w.y); p.z = f2bf(w.z); p.w = f2bf(w.w);
    ((ushort4*)whhb)[i] = p;
  }
  if (i < 16384u) {                                      // h0 -> hbuf[0], c0 -> cst
    float4 v = ((const float4*)h0)[i];
    ushort4 o; o.x = f2bf(v.x); o.y = f2bf(v.y); o.z = f2bf(v.z); o.w = f2bf(v.w);
    ((ushort4*)hbuf)[i] = o;
    ((float4*)cst)[i] = ((const float4*)c0)[i];
  }
  if (i < 4096u) bias[i] = bih[i] + bhh[i];
}

// ---- one 128x128 x_proj tile; epilogue scatters into consumer layout ----
// xpl element addr: t*262144 + gw*512 + l*8 + slot, where for (batch b, gate g, unit u):
//   gw = (u>>3)*4 + (b>>4); l = ((b&15)<<2)|((u>>1)&3); slot = g*2 + (u&1)
__device__ __forceinline__ void gemm_tile(const u16* __restrict__ xb,
                                          const u16* __restrict__ wihb,
                                          u16* __restrict__ xpl, int s0,
                                          int mt, int nt, int t, char* smem) {
  u16* lds = (u16*)smem;                     // A bytes [0,16384), B bytes [16384,32768)
  const bool act = t < 256;
  const int lane = t & 63, w = t >> 6;
  const int wm = (w >> 1) * 64, wn = (w & 1) * 64;
  const int lr = lane & 15, lk = lane >> 4;
  f4v acc[4][4] = {};
  const size_t arow0 = (size_t)(mt * 512 + s0) * 1024;
  const size_t brow0 = (size_t)(nt * 128) * 1024;
  for (int k0 = 0; k0 < 1024; k0 += 64) {
    if (act) {
      #pragma unroll
      for (int i = 0; i < 4; i++) {          // stage A,B tiles [128][64] bf16, XOR swizzled
        int f16 = i * 256 + t;
        int row = f16 >> 3;
        int colb = (f16 & 7) << 4;
        int dst = row * 128 + (colb ^ ((row & 7) << 4));
        s8v va = *(const s8v*)(xb + arow0 + (size_t)row * 1024 + k0 + (colb >> 1));
        *(s8v*)((char*)lds + dst) = va;
        s8v vb = *(const s8v*)(wihb + brow0 + (size_t)row * 1024 + k0 + (colb >> 1));
        *(s8v*)((char*)lds + 16384 + dst) = vb;
      }
    }
    __syncthreads();
    if (act) {
      #pragma unroll
      for (int ks = 0; ks < 2; ks++) {
        s8v af[4], bf[4];
        #pragma unroll
        for (int mi = 0; mi < 4; mi++) {
          int r = wm + mi * 16 + lr;
          int cb = (ks * 64 + lk * 16) ^ ((r & 7) << 4);
          af[mi] = *(const s8v*)((const char*)lds + r * 128 + cb);
        }
        #pragma unroll
        for (int ni = 0; ni < 4; ni++) {
          int r = wn + ni * 16 + lr;
          int cb = (ks * 64 + lk * 16) ^ ((r & 7) << 4);
          bf[ni] = *(const s8v*)((const char*)lds + 16384 + r * 128 + cb);
        }
        #pragma unroll
        for (int mi = 0; mi < 4; mi++)
          #pragma unroll
          for (int ni = 0; ni < 4; ni++)
            acc[mi][ni] = __builtin_amdgcn_mfma_f32_16x16x32_bf16(af[mi], bf[ni], acc[mi][ni], 0, 0, 0);
      }
    }
    __syncthreads();
  }
  if (act) {
    int nioff[4];
    const int bq = mt >> 4, b15 = mt & 15;
    #pragma unroll
    for (int ni = 0; ni < 4; ni++) {
      int col = nt * 128 + wn + ni * 16 + lr;
      int gate = col >> 10, u = col & 1023;
      int gw = (u >> 3) * 4 + bq;
      int l = (b15 << 2) | ((u >> 1) & 3);
      nioff[ni] = gw * 512 + l * 8 + gate * 2 + (u & 1);
    }
    #pragma unroll
    for (int mi = 0; mi < 4; mi++)
      #pragma unroll
      for (int rr = 0; rr < 4; rr++) {
        int tloc = wm + mi * 16 + lk * 4 + rr;
        u16* dst = xpl + (size_t)tloc * 262144;
        #pragma unroll
        for (int ni = 0; ni < 4; ni++) dst[nioff[ni]] = f2bf(acc[mi][ni][rr]);
      }
  }
}

// ---------------- standalone GEMM for chunk 0 ----------------
__global__ __launch_bounds__(256, 2) void k_gemm(const u16* __restrict__ xb,
                                                 const u16* __restrict__ wihb,
                                                 u16* __restrict__ xpl, int s0) {
  __shared__ __align__(16) char smem[32768];
  const int bx = blockIdx.x;                 // 2048 = 64 mt * 32 nt
  gemm_tile(xb, wihb, xpl, s0, bx >> 5, bx & 31, threadIdx.x, smem);
}

// ---- fused: blocks 0..127 = recurrence(chunk), 128..255 = GEMM(chunk+1) ----
__global__ __launch_bounds__(320, 1) void k_fused(
    const u16* __restrict__ whhb, const u16* __restrict__ xpl_c,
    u16* __restrict__ xpl_n, const float* __restrict__ bias,
    float* __restrict__ cst, u16* __restrict__ hbuf, float* __restrict__ out,
    unsigned* __restrict__ flags, const u16* __restrict__ xb,
    const u16* __restrict__ wihb, int chunk) {
  __shared__ __align__(16) char smem[32768];
  const int bid = blockIdx.x;
  const int t = threadIdx.x;
  if (bid >= NRB) {                          // ---- GEMM role: chunk+1, 16 tiles ----
    if (chunk + 1 < NCH) {
      const int gb = bid - NRB;
      for (int ti = 0; ti < 16; ti++) {
        int tt = gb * 16 + ti;
        gemm_tile(xb, wihb, xpl_n, (chunk + 1) * CH, tt >> 5, tt & 31, t, smem);
      }
    }
    return;
  }
  // ---- recurrence role ----
  const int lane = t & 63, w = t >> 6;
  const unsigned epb = (unsigned)(chunk * CH);
  if (w == 4) {
    // sync wave: polls 128 block flags (64B stride) in two halves, signals via barriers
    const unsigned* fA = flags + lane * 16;          // blocks 0..63  (h units 0..511)
    const unsigned* fB = flags + (64 + lane) * 16;   // blocks 64..127 (units 512..1023)
    for (int tl = 0; tl < CH; tl++) {
      unsigned ep = epb + (unsigned)tl;
      if (tl > 0) {
        for (;;) {
          unsigned fa;
          asm volatile("global_load_dword %0, %1, off sc0 sc1" : "=v"(fa) : "v"(fA) : "memory");
          asm volatile("s_waitcnt vmcnt(0)" ::: "memory");
          if (__all(fa >= ep)) break;
        }
      }
      __builtin_amdgcn_s_barrier();          // BAR_A: h-half A visible
      if (tl > 0) {
        for (;;) {
          unsigned fb;
          asm volatile("global_load_dword %0, %1, off sc0 sc1" : "=v"(fb) : "v"(fB) : "memory");
          asm volatile("s_waitcnt vmcnt(0)" ::: "memory");
          if (__all(fb >= ep)) break;
        }
      }
      __builtin_amdgcn_s_barrier();          // BAR_B: h-half B visible
      __builtin_amdgcn_s_barrier();          // BAR_C: own compute waves acked h(tl+1)
      if (lane == 0) {
        unsigned fv = ep + 1u;
        asm volatile("global_store_dword %0, %1, off sc0 sc1"
                     :: "v"(flags + bid * 16), "v"(fv) : "memory");
      }
    }
    return;
  }
  // compute waves w=0..3
  const int lr = lane & 15, lk = lane >> 4;
  s8v breg[2][32];                           // 2 n-tiles x 32 k-frags of w_hh
  #pragma unroll
  for (int nt = 0; nt < 2; nt++) {
    int grow = (lr >> 2) * 1024 + bid * 8 + nt * 4 + (lr & 3);
    const u16* wp = whhb + (size_t)grow * 1024 + lk * 8;
    #pragma unroll
    for (int ks = 0; ks < 32; ks++) breg[nt][ks] = *(const s8v*)(wp + ks * 32);
  }
  const int me = w * 16 + (lane >> 2);       // batch row owned for elementwise
  const int u0 = bid * 8 + (lane & 3) * 2;   // first of 2 hidden units
  const float2 bi  = *(const float2*)(bias + u0);
  const float2 bff = *(const float2*)(bias + 1024 + u0);
  const float2 bgg = *(const float2*)(bias + 2048 + u0);
  const float2 bo  = *(const float2*)(bias + 3072 + u0);
  float2 c = *(const float2*)(cst + me * 1024 + u0);
  float* glw = (float*)smem + w * (16 * 36); // per-wave gate buffer, padded stride
  int cur = 0;
  for (int tl = 0; tl < CH; tl++) {
    s8v xq;                                  // static x-proj: issue before the wait
    asm volatile("global_load_dwordx4 %0, %1, off"
                 : "=v"(xq) : "v"(xpl_c + (size_t)tl * 262144 + (bid * 4 + w) * 512 + lane * 8) : "memory");
    __builtin_amdgcn_s_barrier();            // BAR_A: half A ready
    const u16* ap = hbuf + cur * 65536 + (w * 16 + lr) * 1024 + lk * 8;
    s8v af[32];
    #pragma unroll
    for (int ks = 0; ks < 16; ks++)
      asm volatile("global_load_dwordx4 %0, %1, off sc0 sc1"
                   : "=v"(af[ks]) : "v"(ap + ks * 32) : "memory");
    f4v acc0 = {0.f, 0.f, 0.f, 0.f}, acc1 = {0.f, 0.f, 0.f, 0.f};
    asm volatile("s_waitcnt vmcnt(0)" ::: "memory");   // xq + afA done
    __builtin_amdgcn_sched_barrier(0);
    #pragma unroll
    for (int ks = 0; ks < 16; ks++) {
      acc0 = __builtin_amdgcn_mfma_f32_16x16x32_bf16(af[ks], breg[0][ks], acc0, 0, 0, 0);
      acc1 = __builtin_amdgcn_mfma_f32_16x16x32_bf16(af[ks], breg[1][ks], acc1, 0, 0, 0);
    }
    __builtin_amdgcn_s_barrier();            // BAR_B: half B ready (detect hidden under A)
    #pragma unroll
    for (int ks = 16; ks < 32; ks++)
      asm volatile("global_load_dwordx4 %0, %1, off sc0 sc1"
                   : "=v"(af[ks]) : "v"(ap + ks * 32) : "memory");
    asm volatile("s_waitcnt vmcnt(0)" ::: "memory");
    __builtin_amdgcn_sched_barrier(0);
    #pragma unroll
    for (int ks = 16; ks < 32; ks++) {
      acc0 = __builtin_amdgcn_mfma_f32_16x16x32_bf16(af[ks], breg[0][ks], acc0, 0, 0, 0);
      acc1 = __builtin_amdgcn_mfma_f32_16x16x32_bf16(af[ks], breg[1][ks], acc1, 0, 0, 0);
    }
    // intra-wave gate transpose via private LDS: [mrow][unit][gate], stride 36
    #pragma unroll
    for (int r = 0; r < 4; r++) {
      int mrow = lk * 4 + r;
      glw[mrow * 36 + (lr & 3) * 4 + (lr >> 2)] = acc0[r];
      glw[mrow * 36 + 16 + (lr & 3) * 4 + (lr >> 2)] = acc1[r];
    }
    asm volatile("s_waitcnt lgkmcnt(0)" ::: "memory");
    __builtin_amdgcn_sched_barrier(0);
    float4 q0 = *(const float4*)(glw + (lane >> 2) * 36 + (lane & 3) * 8);
    float4 q1 = *(const float4*)(glw + (lane >> 2) * 36 + (lane & 3) * 8 + 4);
    float pi0 = q0.x + bf2f((u16)xq[0]) + bi.x;
    float pi1 = q1.x + bf2f((u16)xq[1]) + bi.y;
    float pf0 = q0.y + bf2f((u16)xq[2]) + bff.x;
    float pf1 = q1.y + bf2f((u16)xq[3]) + bff.y;
    float pg0 = q0.z + bf2f((u16)xq[4]) + bgg.x;
    float pg1 = q1.z + bf2f((u16)xq[5]) + bgg.y;
    float po0 = q0.w + bf2f((u16)xq[6]) + bo.x;
    float po1 = q1.w + bf2f((u16)xq[7]) + bo.y;
    float i0 = 1.f / (1.f + __expf(-pi0)), i1 = 1.f / (1.f + __expf(-pi1));
    float f0 = 1.f / (1.f + __expf(-pf0)), f1 = 1.f / (1.f + __expf(-pf1));
    float g0 = 1.f - 2.f / (__expf(2.f * pg0) + 1.f), g1 = 1.f - 2.f / (__expf(2.f * pg1) + 1.f);
    float o0 = 1.f / (1.f + __expf(-po0)), o1 = 1.f / (1.f + __expf(-po1));
    c.x = f0 * c.x + i0 * g0;
    c.y = f1 * c.y + i1 * g1;
    float hv0 = o0 * (1.f - 2.f / (__expf(2.f * c.x) + 1.f));
    float hv1 = o1 * (1.f - 2.f / (__expf(2.f * c.y) + 1.f));
    int nxt = cur ^ 1;
    unsigned hw = (unsigned)f2bf(hv0) | ((unsigned)f2bf(hv1) << 16);
    asm volatile("global_store_dword %0, %1, off sc0 sc1"
                 :: "v"(hbuf + nxt * 65536 + me * 1024 + u0), "v"(hw) : "memory");
    if (tl < CH - 1) {
      asm volatile("s_waitcnt vmcnt(0)" ::: "memory");   // own h-slice acked at LLC
    } else {
      if (chunk == NCH - 1) *(float2*)(out + me * 1024 + u0) = make_float2(hv0, hv1);
      else *(float2*)(cst + me * 1024 + u0) = c;
    }
    __builtin_amdgcn_s_barrier();            // BAR_C: all compute waves acked
    cur = nxt;
  }
}

extern "C" void kernel_launch(void* const* d_in, const int* in_sizes, int n_in,
                              void* d_out, int out_size, void* d_ws, size_t ws_size,
                              hipStream_t stream) {
  const float* x   = (const float*)d_in[0];
  const float* h0  = (const float*)d_in[1];
  const float* c0  = (const float*)d_in[2];
  const float* wih = (const float*)d_in[3];
  const float* whh = (const float*)d_in[4];
  const float* bih = (const float*)d_in[5];
  const float* bhh = (const float*)d_in[6];
  float* out = (float*)d_out;
  char* ws = (char*)d_ws;
  u16* xb     = (u16*)(ws);                       // 64 MB  x bf16
  u16* wihb   = (u16*)(ws + 67108864);            // 8 MB
  u16* whhb   = (u16*)(ws + 75497472);            // 8 MB
  float* bias = (float*)(ws + 83886080);          // 16 KB
  u16* hbuf   = (u16*)(ws + 83902464);            // 256 KB (2 buffers)
  float* cst  = (float*)(ws + 84164608);          // 256 KB
  unsigned* flags = (unsigned*)(ws + 84426752);   // 16 KB (128 flags, 64B stride)
  u16* xpl0   = (u16*)(ws + 84443136);            // 64 MB x_proj chunk buffer (even)
  u16* xpl1   = (u16*)(ws + 151552000);           // 64 MB x_proj chunk buffer (odd)
  (void)in_sizes; (void)n_in; (void)out_size; (void)ws_size;

  hipMemsetAsync(flags, 0, 16384, stream);
  hipLaunchKernelGGL(k_cast, dim3(8192), dim3(256), 0, stream,
                     x, wih, whh, bih, bhh, h0, c0, xb, wihb, whhb, bias, hbuf, cst);
  hipLaunchKernelGGL(k_gemm, dim3(2048), dim3(256), 0, stream, xb, wihb, xpl0, 0);
  for (int c = 0; c < NCH; c++) {
    u16* xc = (c & 1) ? xpl1 : xpl0;
    u16* xn = (c & 1) ? xpl0 : xpl1;
    hipLaunchKernelGGL(k_fused, dim3(256), dim3(320), 0, stream,
                       whhb, xc, xn, bias, cst, hbuf, out, flags, xb, wihb, c);
  }
}

// Round 9
// 3548.978 us; speedup vs baseline: 1.5273x; 1.5273x over previous
//
#include <hip/hip_runtime.h>

typedef short s8v __attribute__((ext_vector_type(8)));   // 8 x bf16 bits
typedef float f4v __attribute__((ext_vector_type(4)));
typedef unsigned short u16;

#define CH 128          // timesteps per chunk
#define NCH 4
#define NRB 128         // rec blocks; each owns 8 hidden units (32 gate cols)

__device__ __forceinline__ u16 f2bf(float f) {
  unsigned u = __builtin_bit_cast(unsigned, f);
  u = (u + 0x7fffu + ((u >> 16) & 1u)) >> 16;
  return (u16)u;
}
__device__ __forceinline__ float bf2f(u16 h) {
  unsigned u = ((unsigned)h) << 16;
  return __builtin_bit_cast(float, u);
}

// ------- cast inputs to bf16, combine bias, stage h0 (bf16) and c0 -------
__global__ void k_cast(const float* __restrict__ x, const float* __restrict__ wih,
                       const float* __restrict__ whh, const float* __restrict__ bih,
                       const float* __restrict__ bhh, const float* __restrict__ h0,
                       const float* __restrict__ c0, u16* __restrict__ xb,
                       u16* __restrict__ wihb, u16* __restrict__ whhb,
                       float* __restrict__ bias, u16* __restrict__ hbuf,
                       float* __restrict__ cst) {
  unsigned i = blockIdx.x * 256u + threadIdx.x;
  const unsigned NT = 8192u * 256u;
  for (unsigned j = i; j < 8388608u; j += NT) {          // x: 33.5M els as float4
    float4 v = ((const float4*)x)[j];
    ushort4 o; o.x = f2bf(v.x); o.y = f2bf(v.y); o.z = f2bf(v.z); o.w = f2bf(v.w);
    ((ushort4*)xb)[j] = o;
  }
  if (i < 1048576u) {                                    // w_ih, w_hh
    float4 v = ((const float4*)wih)[i];
    ushort4 o; o.x = f2bf(v.x); o.y = f2bf(v.y); o.z = f2bf(v.z); o.w = f2bf(v.w);
    ((ushort4*)wihb)[i] = o;
    float4 w = ((const float4*)whh)[i];
    ushort4 p; p.x = f2bf(w.x); p.y = f2bf(w.y); p.z = f2bf(w.z); p.w = f2bf(w.w);
    ((ushort4*)whhb)[i] = p;
  }
  if (i < 16384u) {                                      // h0 -> hbuf[0], c0 -> cst
    float4 v = ((const float4*)h0)[i];
    ushort4 o; o.x = f2bf(v.x); o.y = f2bf(v.y); o.z = f2bf(v.z); o.w = f2bf(v.w);
    ((ushort4*)hbuf)[i] = o;
    ((float4*)cst)[i] = ((const float4*)c0)[i];
  }
  if (i < 4096u) bias[i] = bih[i] + bhh[i];
}

// ---- one 128x128 x_proj tile; epilogue scatters into consumer layout ----
// xpl element addr: t*262144 + gw*512 + l*8 + slot, for (batch b, gate g, unit u):
//   gw = (u>>3)*4 + (b>>4); l = ((b&15)<<2)|((u>>1)&3); slot = g*2 + (u&1)
__device__ __forceinline__ void gemm_tile(const u16* __restrict__ xb,
                                          const u16* __restrict__ wihb,
                                          u16* __restrict__ xpl, int s0,
                                          int mt, int nt, int t, char* smem) {
  u16* lds = (u16*)smem;                     // A bytes [0,16384), B bytes [16384,32768)
  const int lane = t & 63, w = t >> 6;
  const int wm = (w >> 1) * 64, wn = (w & 1) * 64;
  const int lr = lane & 15, lk = lane >> 4;
  f4v acc[4][4] = {};
  const size_t arow0 = (size_t)(mt * 512 + s0) * 1024;
  const size_t brow0 = (size_t)(nt * 128) * 1024;
  for (int k0 = 0; k0 < 1024; k0 += 64) {
    #pragma unroll
    for (int i = 0; i < 4; i++) {            // stage A,B tiles [128][64] bf16, XOR swizzled
      int f16 = i * 256 + t;
      int row = f16 >> 3;
      int colb = (f16 & 7) << 4;
      int dst = row * 128 + (colb ^ ((row & 7) << 4));
      s8v va = *(const s8v*)(xb + arow0 + (size_t)row * 1024 + k0 + (colb >> 1));
      *(s8v*)((char*)lds + dst) = va;
      s8v vb = *(const s8v*)(wihb + brow0 + (size_t)row * 1024 + k0 + (colb >> 1));
      *(s8v*)((char*)lds + 16384 + dst) = vb;
    }
    __syncthreads();
    #pragma unroll
    for (int ks = 0; ks < 2; ks++) {
      s8v af[4], bf[4];
      #pragma unroll
      for (int mi = 0; mi < 4; mi++) {
        int r = wm + mi * 16 + lr;
        int cb = (ks * 64 + lk * 16) ^ ((r & 7) << 4);
        af[mi] = *(const s8v*)((const char*)lds + r * 128 + cb);
      }
      #pragma unroll
      for (int ni = 0; ni < 4; ni++) {
        int r = wn + ni * 16 + lr;
        int cb = (ks * 64 + lk * 16) ^ ((r & 7) << 4);
        bf[ni] = *(const s8v*)((const char*)lds + 16384 + r * 128 + cb);
      }
      #pragma unroll
      for (int mi = 0; mi < 4; mi++)
        #pragma unroll
        for (int ni = 0; ni < 4; ni++)
          acc[mi][ni] = __builtin_amdgcn_mfma_f32_16x16x32_bf16(af[mi], bf[ni], acc[mi][ni], 0, 0, 0);
    }
    __syncthreads();
  }
  int nioff[4];
  const int bq = mt >> 4, b15 = mt & 15;
  #pragma unroll
  for (int ni = 0; ni < 4; ni++) {
    int col = nt * 128 + wn + ni * 16 + lr;
    int gate = col >> 10, u = col & 1023;
    int gw = (u >> 3) * 4 + bq;
    int l = (b15 << 2) | ((u >> 1) & 3);
    nioff[ni] = gw * 512 + l * 8 + gate * 2 + (u & 1);
  }
  #pragma unroll
  for (int mi = 0; mi < 4; mi++)
    #pragma unroll
    for (int rr = 0; rr < 4; rr++) {
      int tloc = wm + mi * 16 + lk * 4 + rr;
      u16* dst = xpl + (size_t)tloc * 262144;
      #pragma unroll
      for (int ni = 0; ni < 4; ni++) dst[nioff[ni]] = f2bf(acc[mi][ni][rr]);
    }
}

// ---------------- standalone GEMM for chunk 0 ----------------
__global__ __launch_bounds__(256, 2) void k_gemm(const u16* __restrict__ xb,
                                                 const u16* __restrict__ wihb,
                                                 u16* __restrict__ xpl, int s0) {
  __shared__ __align__(16) char smem[32768];
  const int bx = blockIdx.x;                 // 2048 = 64 mt * 32 nt
  gemm_tile(xb, wihb, xpl, s0, bx >> 5, bx & 31, threadIdx.x, smem);
}

// ------- block-level barrier (R3-proven): wave0 stores flag + polls 128 flags -------
__device__ __forceinline__ void gbar2(unsigned* flags, unsigned ep) {
  __syncthreads();                            // all waves drained vmcnt before entry
  if (threadIdx.x < 64) {
    if (threadIdx.x == 0)
      __hip_atomic_store(flags + (size_t)blockIdx.x * 16, ep,
                         __ATOMIC_RELAXED, __HIP_MEMORY_SCOPE_AGENT);
    const int l = threadIdx.x;
    for (;;) {
      unsigned a = __hip_atomic_load(flags + l * 16,        __ATOMIC_RELAXED, __HIP_MEMORY_SCOPE_AGENT);
      unsigned b = __hip_atomic_load(flags + (l + 64) * 16, __ATOMIC_RELAXED, __HIP_MEMORY_SCOPE_AGENT);
      if (__all(a >= ep && b >= ep)) break;
    }
  }
  __syncthreads();
}

// ---- fused: blocks 0..127 = recurrence(chunk), 128..255 = GEMM(chunk+1) ----
__global__ __launch_bounds__(256, 1) void k_fused(
    const u16* __restrict__ whhb, const u16* __restrict__ xpl_c,
    u16* __restrict__ xpl_n, const float* __restrict__ bias,
    float* __restrict__ cst, u16* __restrict__ hbuf, float* __restrict__ out,
    unsigned* __restrict__ flags, const u16* __restrict__ xb,
    const u16* __restrict__ wihb, int chunk) {
  __shared__ __align__(16) char smem[32768];
  const int bid = blockIdx.x;
  const int t = threadIdx.x;
  if (bid >= NRB) {                          // ---- GEMM role: chunk+1, 16 tiles ----
    if (chunk + 1 < NCH) {
      const int gb = bid - NRB;
      for (int ti = 0; ti < 16; ti++) {
        int tt = gb * 16 + ti;
        gemm_tile(xb, wihb, xpl_n, (chunk + 1) * CH, tt >> 5, tt & 31, t, smem);
      }
    }
    return;
  }
  // ---- recurrence role (R5-proven body + R3-proven barrier) ----
  const int lane = t & 63, w = t >> 6, lr = lane & 15, lk = lane >> 4;
  s8v breg[2][32];                           // w_hh fragments, resident in regs
  #pragma unroll
  for (int nt = 0; nt < 2; nt++) {
    int grow = (lr >> 2) * 1024 + bid * 8 + nt * 4 + (lr & 3);
    const u16* wp = whhb + (size_t)grow * 1024 + lk * 8;
    #pragma unroll
    for (int ks = 0; ks < 32; ks++) breg[nt][ks] = *(const s8v*)(wp + ks * 32);
  }
  const int me = w * 16 + (lane >> 2);       // batch row owned for elementwise
  const int u0 = bid * 8 + (lane & 3) * 2;   // first of 2 hidden units
  const float2 bi  = *(const float2*)(bias + u0);
  const float2 bff = *(const float2*)(bias + 1024 + u0);
  const float2 bgg = *(const float2*)(bias + 2048 + u0);
  const float2 bo  = *(const float2*)(bias + 3072 + u0);
  float2 c = *(const float2*)(cst + me * 1024 + u0);
  float* glw = (float*)smem + w * (16 * 36); // per-wave gate buffer, padded stride
  const unsigned epb = (unsigned)(chunk * CH);
  int cur = 0;
  for (int tl = 0; tl < CH; tl++) {
    s8v xq;                                  // static x-proj: one dwordx4/lane
    asm volatile("global_load_dwordx4 %0, %1, off"
                 : "=v"(xq) : "v"(xpl_c + (size_t)tl * 262144 + (bid * 4 + w) * 512 + lane * 8) : "memory");
    // h fragment loads (LLC-coherent)
    const u16* ap = hbuf + cur * 65536 + (w * 16 + lr) * 1024 + lk * 8;
    s8v af[32];
    #pragma unroll
    for (int ks = 0; ks < 32; ks++)
      asm volatile("global_load_dwordx4 %0, %1, off sc0 sc1"
                   : "=v"(af[ks]) : "v"(ap + ks * 32) : "memory");
    f4v acc0 = {0.f, 0.f, 0.f, 0.f}, acc1 = {0.f, 0.f, 0.f, 0.f};
    asm volatile("s_waitcnt vmcnt(16)" ::: "memory");
    __builtin_amdgcn_sched_barrier(0);
    #pragma unroll
    for (int ks = 0; ks < 16; ks++) {
      acc0 = __builtin_amdgcn_mfma_f32_16x16x32_bf16(af[ks], breg[0][ks], acc0, 0, 0, 0);
      acc1 = __builtin_amdgcn_mfma_f32_16x16x32_bf16(af[ks], breg[1][ks], acc1, 0, 0, 0);
    }
    asm volatile("s_waitcnt vmcnt(0)" ::: "memory");
    __builtin_amdgcn_sched_barrier(0);
    #pragma unroll
    for (int ks = 16; ks < 32; ks++) {
      acc0 = __builtin_amdgcn_mfma_f32_16x16x32_bf16(af[ks], breg[0][ks], acc0, 0, 0, 0);
      acc1 = __builtin_amdgcn_mfma_f32_16x16x32_bf16(af[ks], breg[1][ks], acc1, 0, 0, 0);
    }
    // intra-wave gate transpose via private LDS: [mrow][unit][gate], stride 36
    #pragma unroll
    for (int r = 0; r < 4; r++) {
      int mrow = lk * 4 + r;
      glw[mrow * 36 + (lr & 3) * 4 + (lr >> 2)] = acc0[r];
      glw[mrow * 36 + 16 + (lr & 3) * 4 + (lr >> 2)] = acc1[r];
    }
    asm volatile("s_waitcnt lgkmcnt(0)" ::: "memory");
    __builtin_amdgcn_sched_barrier(0);
    float4 q0 = *(const float4*)(glw + (lane >> 2) * 36 + (lane & 3) * 8);
    float4 q1 = *(const float4*)(glw + (lane >> 2) * 36 + (lane & 3) * 8 + 4);
    float pi0 = q0.x + bf2f((u16)xq[0]) + bi.x;
    float pi1 = q1.x + bf2f((u16)xq[1]) + bi.y;
    float pf0 = q0.y + bf2f((u16)xq[2]) + bff.x;
    float pf1 = q1.y + bf2f((u16)xq[3]) + bff.y;
    float pg0 = q0.z + bf2f((u16)xq[4]) + bgg.x;
    float pg1 = q1.z + bf2f((u16)xq[5]) + bgg.y;
    float po0 = q0.w + bf2f((u16)xq[6]) + bo.x;
    float po1 = q1.w + bf2f((u16)xq[7]) + bo.y;
    float i0 = 1.f / (1.f + __expf(-pi0)), i1 = 1.f / (1.f + __expf(-pi1));
    float f0 = 1.f / (1.f + __expf(-pf0)), f1 = 1.f / (1.f + __expf(-pf1));
    float g0 = 1.f - 2.f / (__expf(2.f * pg0) + 1.f), g1 = 1.f - 2.f / (__expf(2.f * pg1) + 1.f);
    float o0 = 1.f / (1.f + __expf(-po0)), o1 = 1.f / (1.f + __expf(-po1));
    c.x = f0 * c.x + i0 * g0;
    c.y = f1 * c.y + i1 * g1;
    float hv0 = o0 * (1.f - 2.f / (__expf(2.f * c.x) + 1.f));
    float hv1 = o1 * (1.f - 2.f / (__expf(2.f * c.y) + 1.f));
    int nxt = cur ^ 1;
    unsigned hw = (unsigned)f2bf(hv0) | ((unsigned)f2bf(hv1) << 16);
    asm volatile("global_store_dword %0, %1, off sc0 sc1"
                 :: "v"(hbuf + nxt * 65536 + me * 1024 + u0), "v"(hw) : "memory");
    cur = nxt;
    if (tl < CH - 1) {
      asm volatile("s_waitcnt vmcnt(0)" ::: "memory");   // own h-slice acked at LLC
      gbar2(flags, epb + (unsigned)tl + 1u);
    } else {
      if (chunk == NCH - 1) *(float2*)(out + me * 1024 + u0) = make_float2(hv0, hv1);
      else *(float2*)(cst + me * 1024 + u0) = c;
    }
  }
}

extern "C" void kernel_launch(void* const* d_in, const int* in_sizes, int n_in,
                              void* d_out, int out_size, void* d_ws, size_t ws_size,
                              hipStream_t stream) {
  const float* x   = (const float*)d_in[0];
  const float* h0  = (const float*)d_in[1];
  const float* c0  = (const float*)d_in[2];
  const float* wih = (const float*)d_in[3];
  const float* whh = (const float*)d_in[4];
  const float* bih = (const float*)d_in[5];
  const float* bhh = (const float*)d_in[6];
  float* out = (float*)d_out;
  char* ws = (char*)d_ws;
  u16* xb     = (u16*)(ws);                       // 64 MB  x bf16
  u16* wihb   = (u16*)(ws + 67108864);            // 8 MB
  u16* whhb   = (u16*)(ws + 75497472);            // 8 MB
  float* bias = (float*)(ws + 83886080);          // 16 KB
  u16* hbuf   = (u16*)(ws + 83902464);            // 256 KB (2 buffers)
  float* cst  = (float*)(ws + 84164608);          // 256 KB
  unsigned* flags = (unsigned*)(ws + 84426752);   // 16 KB (128 flags, 64B stride)
  u16* xpl0   = (u16*)(ws + 84443136);            // 64 MB x_proj chunk buffer (even)
  u16* xpl1   = (u16*)(ws + 151552000);           // 64 MB x_proj chunk buffer (odd)
  (void)in_sizes; (void)n_in; (void)out_size; (void)ws_size;

  hipMemsetAsync(flags, 0, 16384, stream);
  hipLaunchKernelGGL(k_cast, dim3(8192), dim3(256), 0, stream,
                     x, wih, whh, bih, bhh, h0, c0, xb, wihb, whhb, bias, hbuf, cst);
  hipLaunchKernelGGL(k_gemm, dim3(2048), dim3(256), 0, stream, xb, wihb, xpl0, 0);
  for (int c = 0; c < NCH; c++) {
    u16* xc = (c & 1) ? xpl1 : xpl0;
    u16* xn = (c & 1) ? xpl0 : xpl1;
    hipLaunchKernelGGL(k_fused, dim3(256), dim3(256), 0, stream,
                       whhb, xc, xn, bias, cst, hbuf, out, flags, xb, wihb, c);
  }
}

// Round 11
// 3467.093 us; speedup vs baseline: 1.5634x; 1.0236x over previous
//
#include <hip/hip_runtime.h>

typedef short s8v __attribute__((ext_vector_type(8)));   // 8 x bf16 bits
typedef float f4v __attribute__((ext_vector_type(4)));
typedef int   i4v __attribute__((ext_vector_type(4)));
typedef unsigned short u16;
typedef unsigned char u8;

#define CH 128          // timesteps per chunk
#define NCH 4
#define NRB 128         // rec blocks; each owns 8 hidden units (32 gate cols)

__device__ __forceinline__ u16 f2bf(float f) {
  unsigned u = __builtin_bit_cast(unsigned, f);
  u = (u + 0x7fffu + ((u >> 16) & 1u)) >> 16;
  return (u16)u;
}
__device__ __forceinline__ float bf2f(u16 h) {
  unsigned u = ((unsigned)h) << 16;
  return __builtin_bit_cast(float, u);
}
__device__ __forceinline__ int q8(float f, float s) {    // round-to-nearest int8
  return (int)rintf(f * s);
}

// -- cast: x,w_ih -> bf16; w_hh -> i8 (x4064); bias; h0 -> i8 slot0 (x25.4); c0 --
__global__ void k_cast(const float* __restrict__ x, const float* __restrict__ wih,
                       const float* __restrict__ whh, const float* __restrict__ bih,
                       const float* __restrict__ bhh, const float* __restrict__ h0,
                       const float* __restrict__ c0, u16* __restrict__ xb,
                       u16* __restrict__ wihb, u8* __restrict__ whh8,
                       float* __restrict__ bias, u8* __restrict__ hbuf8,
                       float* __restrict__ cst) {
  unsigned i = blockIdx.x * 256u + threadIdx.x;
  const unsigned NT = 8192u * 256u;
  for (unsigned j = i; j < 8388608u; j += NT) {          // x: 33.5M els as float4
    float4 v = ((const float4*)x)[j];
    ushort4 o; o.x = f2bf(v.x); o.y = f2bf(v.y); o.z = f2bf(v.z); o.w = f2bf(v.w);
    ((ushort4*)xb)[j] = o;
  }
  if (i < 1048576u) {                                    // w_ih bf16; w_hh i8
    float4 v = ((const float4*)wih)[i];
    ushort4 o; o.x = f2bf(v.x); o.y = f2bf(v.y); o.z = f2bf(v.z); o.w = f2bf(v.w);
    ((ushort4*)wihb)[i] = o;
    float4 w = ((const float4*)whh)[i];
    unsigned p = ((unsigned)(q8(w.x, 4064.f) & 255)) |
                 ((unsigned)(q8(w.y, 4064.f) & 255) << 8) |
                 ((unsigned)(q8(w.z, 4064.f) & 255) << 16) |
                 ((unsigned)(q8(w.w, 4064.f) & 255) << 24);
    ((unsigned*)whh8)[i] = p;
  }
  if (i < 16384u) {                                      // h0 -> i8 slot0, c0 -> cst
    float4 v = ((const float4*)h0)[i];
    unsigned p = ((unsigned)(q8(v.x, 25.4f) & 255)) |
                 ((unsigned)(q8(v.y, 25.4f) & 255) << 8) |
                 ((unsigned)(q8(v.z, 25.4f) & 255) << 16) |
                 ((unsigned)(q8(v.w, 25.4f) & 255) << 24);
    ((unsigned*)hbuf8)[i] = p;
    ((float4*)cst)[i] = ((const float4*)c0)[i];
  }
  if (i < 4096u) bias[i] = bih[i] + bhh[i];
}

// ---- one 128x128 x_proj tile; epilogue scatters into consumer layout ----
// xpl element addr: t*262144 + gw*512 + l*8 + slot, for (batch b, gate g, unit u):
//   gw = (u>>3)*4 + (b>>4); l = ((b&15)<<2)|((u>>1)&3); slot = g*2 + (u&1)
__device__ __forceinline__ void gemm_tile(const u16* __restrict__ xb,
                                          const u16* __restrict__ wihb,
                                          u16* __restrict__ xpl, int s0,
                                          int mt, int nt, int t, char* smem) {
  u16* lds = (u16*)smem;                     // A bytes [0,16384), B bytes [16384,32768)
  const int lane = t & 63, w = t >> 6;
  const int wm = (w >> 1) * 64, wn = (w & 1) * 64;
  const int lr = lane & 15, lk = lane >> 4;
  f4v acc[4][4] = {};
  const size_t arow0 = (size_t)(mt * 512 + s0) * 1024;
  const size_t brow0 = (size_t)(nt * 128) * 1024;
  for (int k0 = 0; k0 < 1024; k0 += 64) {
    #pragma unroll
    for (int i = 0; i < 4; i++) {            // stage A,B tiles [128][64] bf16, XOR swizzled
      int f16 = i * 256 + t;
      int row = f16 >> 3;
      int colb = (f16 & 7) << 4;
      int dst = row * 128 + (colb ^ ((row & 7) << 4));
      s8v va = *(const s8v*)(xb + arow0 + (size_t)row * 1024 + k0 + (colb >> 1));
      *(s8v*)((char*)lds + dst) = va;
      s8v vb = *(const s8v*)(wihb + brow0 + (size_t)row * 1024 + k0 + (colb >> 1));
      *(s8v*)((char*)lds + 16384 + dst) = vb;
    }
    __syncthreads();
    #pragma unroll
    for (int ks = 0; ks < 2; ks++) {
      s8v af[4], bf[4];
      #pragma unroll
      for (int mi = 0; mi < 4; mi++) {
        int r = wm + mi * 16 + lr;
        int cb = (ks * 64 + lk * 16) ^ ((r & 7) << 4);
        af[mi] = *(const s8v*)((const char*)lds + r * 128 + cb);
      }
      #pragma unroll
      for (int ni = 0; ni < 4; ni++) {
        int r = wn + ni * 16 + lr;
        int cb = (ks * 64 + lk * 16) ^ ((r & 7) << 4);
        bf[ni] = *(const s8v*)((const char*)lds + 16384 + r * 128 + cb);
      }
      #pragma unroll
      for (int mi = 0; mi < 4; mi++)
        #pragma unroll
        for (int ni = 0; ni < 4; ni++)
          acc[mi][ni] = __builtin_amdgcn_mfma_f32_16x16x32_bf16(af[mi], bf[ni], acc[mi][ni], 0, 0, 0);
    }
    __syncthreads();
  }
  int nioff[4];
  const int bq = mt >> 4, b15 = mt & 15;
  #pragma unroll
  for (int ni = 0; ni < 4; ni++) {
    int col = nt * 128 + wn + ni * 16 + lr;
    int gate = col >> 10, u = col & 1023;
    int gw = (u >> 3) * 4 + bq;
    int l = (b15 << 2) | ((u >> 1) & 3);
    nioff[ni] = gw * 512 + l * 8 + gate * 2 + (u & 1);
  }
  #pragma unroll
  for (int mi = 0; mi < 4; mi++)
    #pragma unroll
    for (int rr = 0; rr < 4; rr++) {
      int tloc = wm + mi * 16 + lk * 4 + rr;
      u16* dst = xpl + (size_t)tloc * 262144;
      #pragma unroll
      for (int ni = 0; ni < 4; ni++) dst[nioff[ni]] = f2bf(acc[mi][ni][rr]);
    }
}

// ---------------- standalone GEMM for chunk 0 ----------------
__global__ __launch_bounds__(256, 2) void k_gemm(const u16* __restrict__ xb,
                                                 const u16* __restrict__ wihb,
                                                 u16* __restrict__ xpl, int s0) {
  __shared__ __align__(16) char smem[32768];
  const int bx = blockIdx.x;                 // 2048 = 64 mt * 32 nt
  gemm_tile(xb, wihb, xpl, s0, bx >> 5, bx & 31, threadIdx.x, smem);
}

// ------- block-level barrier (R3/R9-proven): wave0 stores flag + polls 128 flags -------
__device__ __forceinline__ void gbar2(unsigned* flags, unsigned ep) {
  __syncthreads();                            // all waves drained vmcnt before entry
  if (threadIdx.x < 64) {
    if (threadIdx.x == 0)
      __hip_atomic_store(flags + (size_t)blockIdx.x * 16, ep,
                         __ATOMIC_RELAXED, __HIP_MEMORY_SCOPE_AGENT);
    const int l = threadIdx.x;
    for (;;) {
      unsigned a = __hip_atomic_load(flags + l * 16,        __ATOMIC_RELAXED, __HIP_MEMORY_SCOPE_AGENT);
      unsigned b = __hip_atomic_load(flags + (l + 64) * 16, __ATOMIC_RELAXED, __HIP_MEMORY_SCOPE_AGENT);
      if (__all(a >= ep && b >= ep)) break;
    }
  }
  __syncthreads();
}

// ---- fused: blocks 0..127 = recurrence(chunk) [i8 h exchange], 128..255 = GEMM(chunk+1) ----
__global__ __launch_bounds__(256, 1) void k_fused(
    const u8* __restrict__ whh8, const u16* __restrict__ xpl_c,
    u16* __restrict__ xpl_n, const float* __restrict__ bias,
    float* __restrict__ cst, u8* __restrict__ hbuf8, float* __restrict__ out,
    unsigned* __restrict__ flags, const u16* __restrict__ xb,
    const u16* __restrict__ wihb, int chunk) {
  __shared__ __align__(16) char smem[32768];
  const int bid = blockIdx.x;
  const int t = threadIdx.x;
  if (bid >= NRB) {                          // ---- GEMM role: chunk+1, 16 tiles ----
    if (chunk + 1 < NCH) {
      const int gb = bid - NRB;
      for (int ti = 0; ti < 16; ti++) {
        int tt = gb * 16 + ti;
        gemm_tile(xb, wihb, xpl_n, (chunk + 1) * CH, tt >> 5, tt & 31, t, smem);
      }
    }
    return;
  }
  // ---- recurrence role ----
  const int lane = t & 63, w = t >> 6, lr = lane & 15, lk = lane >> 4;
  long breg[2][32];                          // w_hh i8 fragments (8 B each), in regs
  #pragma unroll
  for (int nt = 0; nt < 2; nt++) {
    int grow = (lr >> 2) * 1024 + bid * 8 + nt * 4 + (lr & 3);
    const u8* wp = whh8 + (size_t)grow * 1024 + lk * 8;
    #pragma unroll
    for (int ks = 0; ks < 32; ks++) breg[nt][ks] = *(const long*)(wp + ks * 32);
  }
  const int me = w * 16 + (lane >> 2);       // batch row owned for elementwise
  const int u0 = bid * 8 + (lane & 3) * 2;   // first of 2 hidden units
  const float2 bi  = *(const float2*)(bias + u0);
  const float2 bff = *(const float2*)(bias + 1024 + u0);
  const float2 bgg = *(const float2*)(bias + 2048 + u0);
  const float2 bo  = *(const float2*)(bias + 3072 + u0);
  float2 c = *(const float2*)(cst + me * 1024 + u0);
  float* glw = (float*)smem + w * (16 * 36); // per-wave gate buffer, padded stride
  const unsigned epb = (unsigned)(chunk * CH);
  int cur = 0;
  for (int tl = 0; tl < CH; tl++) {
    s8v xq;                                  // static x-proj: one dwordx4/lane
    asm volatile("global_load_dwordx4 %0, %1, off"
                 : "=v"(xq) : "v"(xpl_c + (size_t)tl * 262144 + (bid * 4 + w) * 512 + lane * 8) : "memory");
    // h fragment loads: i8, 8 B/frag (LLC-coherent)
    const u8* ap = hbuf8 + cur * 65536 + (w * 16 + lr) * 1024 + lk * 8;
    long af[32];
    #pragma unroll
    for (int ks = 0; ks < 32; ks++)
      asm volatile("global_load_dwordx2 %0, %1, off sc0 sc1"
                   : "=v"(af[ks]) : "v"(ap + ks * 32) : "memory");
    i4v acc0 = {0, 0, 0, 0}, acc1 = {0, 0, 0, 0};
    asm volatile("s_waitcnt vmcnt(16)" ::: "memory");    // xq + af[0..15] done
    __builtin_amdgcn_sched_barrier(0);
    #pragma unroll
    for (int ks = 0; ks < 16; ks++) {
      acc0 = __builtin_amdgcn_mfma_i32_16x16x32_i8(af[ks], breg[0][ks], acc0, 0, 0, 0);
      acc1 = __builtin_amdgcn_mfma_i32_16x16x32_i8(af[ks], breg[1][ks], acc1, 0, 0, 0);
    }
    asm volatile("s_waitcnt vmcnt(0)" ::: "memory");
    __builtin_amdgcn_sched_barrier(0);
    #pragma unroll
    for (int ks = 16; ks < 32; ks++) {
      acc0 = __builtin_amdgcn_mfma_i32_16x16x32_i8(af[ks], breg[0][ks], acc0, 0, 0, 0);
      acc1 = __builtin_amdgcn_mfma_i32_16x16x32_i8(af[ks], breg[1][ks], acc1, 0, 0, 0);
    }
    // scale: h was q/127 (q/25.4 for h0), w was q/4064
    const float gsc = (chunk == 0 && tl == 0) ? (5.f / (127.f * 4064.f))
                                              : (1.f / (127.f * 4064.f));
    // intra-wave gate transpose via private LDS: [mrow][unit][gate], stride 36
    #pragma unroll
    for (int r = 0; r < 4; r++) {
      int mrow = lk * 4 + r;
      glw[mrow * 36 + (lr & 3) * 4 + (lr >> 2)] = (float)acc0[r] * gsc;
      glw[mrow * 36 + 16 + (lr & 3) * 4 + (lr >> 2)] = (float)acc1[r] * gsc;
    }
    asm volatile("s_waitcnt lgkmcnt(0)" ::: "memory");
    __builtin_amdgcn_sched_barrier(0);
    float4 q0 = *(const float4*)(glw + (lane >> 2) * 36 + (lane & 3) * 8);
    float4 q1 = *(const float4*)(glw + (lane >> 2) * 36 + (lane & 3) * 8 + 4);
    float pi0 = q0.x + bf2f((u16)xq[0]) + bi.x;
    float pi1 = q1.x + bf2f((u16)xq[1]) + bi.y;
    float pf0 = q0.y + bf2f((u16)xq[2]) + bff.x;
    float pf1 = q1.y + bf2f((u16)xq[3]) + bff.y;
    float pg0 = q0.z + bf2f((u16)xq[4]) + bgg.x;
    float pg1 = q1.z + bf2f((u16)xq[5]) + bgg.y;
    float po0 = q0.w + bf2f((u16)xq[6]) + bo.x;
    float po1 = q1.w + bf2f((u16)xq[7]) + bo.y;
    float i0 = 1.f / (1.f + __expf(-pi0)), i1 = 1.f / (1.f + __expf(-pi1));
    float f0 = 1.f / (1.f + __expf(-pf0)), f1 = 1.f / (1.f + __expf(-pf1));
    float g0 = 1.f - 2.f / (__expf(2.f * pg0) + 1.f), g1 = 1.f - 2.f / (__expf(2.f * pg1) + 1.f);
    float o0 = 1.f / (1.f + __expf(-po0)), o1 = 1.f / (1.f + __expf(-po1));
    c.x = f0 * c.x + i0 * g0;
    c.y = f1 * c.y + i1 * g1;
    float hv0 = o0 * (1.f - 2.f / (__expf(2.f * c.x) + 1.f));
    float hv1 = o1 * (1.f - 2.f / (__expf(2.f * c.y) + 1.f));
    int nxt = cur ^ 1;
    int qh0 = (int)rintf(hv0 * 127.f), qh1 = (int)rintf(hv1 * 127.f);
    unsigned hw = ((unsigned)(qh0 & 255)) | ((unsigned)(qh1 & 255) << 8);
    asm volatile("global_store_short %0, %1, off sc0 sc1"
                 :: "v"(hbuf8 + nxt * 65536 + me * 1024 + u0), "v"(hw) : "memory");
    cur = nxt;
    if (tl < CH - 1) {
      asm volatile("s_waitcnt vmcnt(0)" ::: "memory");   // own h-slice acked at LLC
      gbar2(flags, epb + (unsigned)tl + 1u);
    } else {
      if (chunk == NCH - 1) *(float2*)(out + me * 1024 + u0) = make_float2(hv0, hv1);
      else *(float2*)(cst + me * 1024 + u0) = c;
    }
  }
}

extern "C" void kernel_launch(void* const* d_in, const int* in_sizes, int n_in,
                              void* d_out, int out_size, void* d_ws, size_t ws_size,
                              hipStream_t stream) {
  const float* x   = (const float*)d_in[0];
  const float* h0  = (const float*)d_in[1];
  const float* c0  = (const float*)d_in[2];
  const float* wih = (const float*)d_in[3];
  const float* whh = (const float*)d_in[4];
  const float* bih = (const float*)d_in[5];
  const float* bhh = (const float*)d_in[6];
  float* out = (float*)d_out;
  char* ws = (char*)d_ws;
  u16* xb     = (u16*)(ws);                       // 64 MB  x bf16
  u16* wihb   = (u16*)(ws + 67108864);            // 8 MB
  u8*  whh8   = (u8*)(ws + 75497472);             // 4 MB  w_hh i8
  float* bias = (float*)(ws + 79691776);          // 16 KB
  u8*  hbuf8  = (u8*)(ws + 79708160);             // 128 KB (2 slots x 64 KB, i8)
  float* cst  = (float*)(ws + 79839232);          // 256 KB
  unsigned* flags = (unsigned*)(ws + 80101376);   // 16 KB (128 flags, 64B stride)
  u16* xpl0   = (u16*)(ws + 80117760);            // 64 MB x_proj chunk buffer (even)
  u16* xpl1   = (u16*)(ws + 147226624);           // 64 MB x_proj chunk buffer (odd)
  (void)in_sizes; (void)n_in; (void)out_size; (void)ws_size;

  hipMemsetAsync(flags, 0, 16384, stream);
  hipLaunchKernelGGL(k_cast, dim3(8192), dim3(256), 0, stream,
                     x, wih, whh, bih, bhh, h0, c0, xb, wihb, whh8, bias, hbuf8, cst);
  hipLaunchKernelGGL(k_gemm, dim3(2048), dim3(256), 0, stream, xb, wihb, xpl0, 0);
  for (int c = 0; c < NCH; c++) {
    u16* xc = (c & 1) ? xpl1 : xpl0;
    u16* xn = (c & 1) ? xpl0 : xpl1;
    hipLaunchKernelGGL(k_fused, dim3(256), dim3(256), 0, stream,
                       whh8, xc, xn, bias, cst, hbuf8, out, flags, xb, wihb, c);
  }
}